// Round 14
// baseline (1301.707 us; speedup 1.0000x reference)
//
#include <hip/hip_runtime.h>
#include <hip/hip_bf16.h>
#include <stdint.h>

// ---------------- problem constants ----------------
#define M_DIM 8192            // B*S = 4*2048
#define N_DIM 11008
#define K_DIM 4096
#define NTILE 64              // K-tiles of 64

typedef unsigned short ushort_t;
typedef __attribute__((ext_vector_type(8))) short  short8;
typedef __attribute__((ext_vector_type(8))) __bf16 bf16x8;
typedef __attribute__((ext_vector_type(4))) float  f32x4;

__device__ __forceinline__ ushort_t f2bf(float f){
  uint32_t u = __builtin_bit_cast(uint32_t, f);
  u += 0x7FFFu + ((u >> 16) & 1u);
  return (ushort_t)(u >> 16);
}

__device__ __forceinline__ void gll16(const void* g, void* l){
  __builtin_amdgcn_global_load_lds(
      (const __attribute__((address_space(1))) void*)g,
      (__attribute__((address_space(3))) void*)l,
      16, 0, 0);
}

// ---------------- pre-pass converts ----------------
__global__ void cvt_x_kernel(const float* __restrict__ x, ushort_t* __restrict__ xb){
  const int TOT = 33554432/8;
  for (int c = blockIdx.x*blockDim.x + threadIdx.x; c < TOT; c += gridDim.x*blockDim.x){
    size_t i = (size_t)c*8;
    float4 v0 = *(const float4*)(x+i);
    float4 v1 = *(const float4*)(x+i+4);
    short8 o;
    o[0]=(short)f2bf(v0.x); o[1]=(short)f2bf(v0.y); o[2]=(short)f2bf(v0.z); o[3]=(short)f2bf(v0.w);
    o[4]=(short)f2bf(v1.x); o[5]=(short)f2bf(v1.y); o[6]=(short)f2bf(v1.z); o[7]=(short)f2bf(v1.w);
    *(short8*)(xb+i) = o;
  }
}

__global__ void cvt_w_kernel(const int* __restrict__ q, const float* __restrict__ scale,
                             const float* __restrict__ zp, ushort_t* __restrict__ wb){
  const int TOT = 45088768/8;
  for (int c = blockIdx.x*blockDim.x + threadIdx.x; c < TOT; c += gridDim.x*blockDim.x){
    int row = c >> 9;
    float s = scale[row];
    float b = -zp[row]*s;
    size_t i = (size_t)c*8;
    int4 q0 = *(const int4*)(q+i);
    int4 q1 = *(const int4*)(q+i+4);
    short8 o;
    o[0]=(short)f2bf((float)q0.x*s+b); o[1]=(short)f2bf((float)q0.y*s+b);
    o[2]=(short)f2bf((float)q0.z*s+b); o[3]=(short)f2bf((float)q0.w*s+b);
    o[4]=(short)f2bf((float)q1.x*s+b); o[5]=(short)f2bf((float)q1.y*s+b);
    o[6]=(short)f2bf((float)q1.z*s+b); o[7]=(short)f2bf((float)q1.w*s+b);
    *(short8*)(wb+i) = o;
  }
}

// == 256x256 8-phase GEMM, one-ahead reads + counted lgkm overlap (r10) ==
// r3/r9 diagnosis: lgkmcnt(0) between each phase's read burst and its MFMA
// serialized LDS (~1000cy/phase across 8 waves) with MFMA (155cy) -> 38%.
// Fix: phase k issues the reads for phase k+1 right AFTER its opening
// barrier, then waits lgkmcnt(N = reads just issued): in-order DS completion
// => phase k's own operands (issued in phase k-1) have landed; the new burst
// drains UNDER phase k's MFMA. No extra registers: the afX/afY/bfX/bfY
// groups' liveness stays disjoint under the shifted issue points (checked
// per phase). One barrier per phase (WAR: reads complete before their
// phase's MFMA => >=1 barrier before any stage of that buffer).
// vmcnt discipline unchanged from r9 (proven): ph4/ph8 stage + VMCNT4
// retires exactly the 4 halves of the buffer being opened (12 outstanding
// -> 4); buf-crossing reads sit AFTER that VMCNT4+BAR. Peeled tail with
// VMCNT0 at ph4 (r4 under-retire fix). sched_barrier(0) after every
// counted wait (rule #18: MFMA hoists past inline-asm waits).
// Issue/wait counts per phase: [4,8,0,12, 4,8,0,12].

#define BAR() do{ asm volatile("" ::: "memory"); \
  __builtin_amdgcn_s_barrier(); \
  asm volatile("" ::: "memory"); }while(0)

#define LGKMW(N) do{ \
  asm volatile("s_waitcnt lgkmcnt(" #N ")" ::: "memory"); \
  __builtin_amdgcn_sched_barrier(0); }while(0)

#define VMCNT4() do{ __builtin_amdgcn_sched_barrier(0); \
  asm volatile("s_waitcnt vmcnt(4)" ::: "memory"); \
  __builtin_amdgcn_sched_barrier(0); }while(0)

#define VMCNT0() do{ __builtin_amdgcn_sched_barrier(0); \
  asm volatile("s_waitcnt vmcnt(0)" ::: "memory"); \
  __builtin_amdgcn_sched_barrier(0); }while(0)

#define LDA_TO(DST, BUF, G) do{ \
  const ushort_t* _b = &As[BUF][wm][((G)*64 + rl)*64]; \
  _Pragma("unroll") for (int mf=0; mf<4; ++mf){ \
    DST[mf][0] = *(const bf16x8*)(_b + mf*1024 + offk0); \
    DST[mf][1] = *(const bf16x8*)(_b + mf*1024 + offk1); } \
}while(0)

#define LDB_TO(DST, BUF, NG) do{ \
  const ushort_t* _b = &Bs[BUF][hb][(hbr + (NG)*32 + rl)*64]; \
  _Pragma("unroll") for (int nfl=0; nfl<2; ++nfl){ \
    DST[nfl][0] = *(const bf16x8*)(_b + nfl*1024 + offk0); \
    DST[nfl][1] = *(const bf16x8*)(_b + nfl*1024 + offk1); } \
}while(0)

#define MFMA_Q(AF, BF, MG, NG) do{ \
  __builtin_amdgcn_s_setprio(1); \
  _Pragma("unroll") for (int mf=0; mf<4; ++mf) \
    _Pragma("unroll") for (int nfl=0; nfl<2; ++nfl) \
      _Pragma("unroll") for (int kk=0; kk<2; ++kk) \
        acc[(MG)*4+mf][(NG)*2+nfl] = __builtin_amdgcn_mfma_f32_16x16x32_bf16( \
            AF[mf][kk], BF[nfl][kk], acc[(MG)*4+mf][(NG)*2+nfl], 0,0,0); \
  __builtin_amdgcn_s_setprio(0); \
}while(0)

#define STAGE_A(BUF, H, T) do{ \
  gll16(aS[H][0] + (size_t)(T)*64, &As[BUF][H][w*1024]); \
  gll16(aS[H][1] + (size_t)(T)*64, &As[BUF][H][w*1024+512]); }while(0)

#define STAGE_B(BUF, H, T) do{ \
  gll16(bS[H][0] + (size_t)(T)*64, &Bs[BUF][H][w*1024]); \
  gll16(bS[H][1] + (size_t)(T)*64, &Bs[BUF][H][w*1024+512]); }while(0)

__global__ __launch_bounds__(512, 1)
void qgemm256(const ushort_t* __restrict__ Xb, const ushort_t* __restrict__ Wb,
              const float* __restrict__ g_bias, float* __restrict__ Y)
{
  __shared__ __align__(16) ushort_t As[2][2][8192];   // 64 KB
  __shared__ __align__(16) ushort_t Bs[2][2][8192];   // 64 KB

  const int t    = threadIdx.x;
  const int lane = t & 63;
  const int w    = t >> 6;        // 0..7
  const int wm   = w >> 2;        // 0..1  (M half)
  const int wn   = w & 3;         // 0..3  (N quarter)
  const int hb   = wn >> 1;       // B half
  const int hbr  = (wn & 1) * 64; // row base within B half

  const int GM2 = M_DIM/256, GN2 = N_DIM/256;   // 32, 43
  const int NWG2 = GM2*GN2;                      // 1376 (%8==0)
  int bid = blockIdx.x;
  int swz = (bid & 7) * (NWG2/8) + (bid >> 3);
  int by = swz / GN2, bx = swz - by*GN2;
  const int brow = by*256, bcol = bx*256;

  const int rl    = lane & 15;
  const int offk0 = (((lane>>4)    ) ^ (lane&7)) * 8;   // kk=0 (elements)
  const int offk1 = (((lane>>4) + 4) ^ (lane&7)) * 8;   // kk=1

  // staging geometry: wave w owns chunks 2w,2w+1 of each half-tile;
  // lane fetches pre-swizzled global slot so LDS lands XOR-swizzled.
  const int g_r = lane >> 3;
  const int g_s = (lane & 7) ^ g_r;
  const ushort_t* aS[2][2];
  const ushort_t* bS[2][2];
  #pragma unroll
  for (int h=0; h<2; ++h)
    #pragma unroll
    for (int ci=0; ci<2; ++ci){
      int r8 = 8*(2*w+ci) + g_r;
      aS[h][ci] = Xb + (size_t)(brow + h*128 + r8)*K_DIM + g_s*8;
      bS[h][ci] = Wb + (size_t)(bcol + h*128 + r8)*K_DIM + g_s*8;
    }

  f32x4 acc[8][4] = {};
  bf16x8 afX[4][2], afY[4][2];   // A fragments: G0 / G1
  bf16x8 bfX[2][2], bfY[2][2];   // B fragments: N0 / N1

  // ---- prologue: buf0 <- tile0 (4 halves), buf1 <- tile1 (B.h0, A.h0) ----
  STAGE_B(0,0,0); STAGE_A(0,0,0); STAGE_A(0,1,0); STAGE_B(0,1,0);
  STAGE_B(1,0,1); STAGE_A(1,0,1);
  VMCNT4();                 // retire buf0's 4 halves; buf1's 2 stay in flight
  BAR();
  LDA_TO(afX, 0, 0);        // ph1 operands (12 reads, in flight)
  LDB_TO(bfX, 0, 0);

  #pragma unroll 1
  for (int j=0; j<NTILE/2-1; ++j){      // j = 0..30
    const int t1 = 2*j+1, t2 = 2*j+2, t3 = 2*j+3;
    // ph1: Q(0,0)@buf0 ; issue bfN1@buf0 for ph2
    STAGE_A(1,1,t1);
    BAR();
    LDB_TO(bfY, 0, 1);
    LGKMW(4);
    MFMA_Q(afX, bfX, 0, 0);
    // ph2: Q(0,1)@buf0 ; issue afG1@buf0 for ph3
    STAGE_B(1,1,t1);
    BAR();
    LDA_TO(afY, 0, 1);
    LGKMW(8);
    MFMA_Q(afX, bfY, 0, 1);
    // ph3: Q(1,0)@buf0 ; ph4 needs no reads
    STAGE_B(0,0,t2);
    BAR();
    LGKMW(0);
    MFMA_Q(afY, bfX, 1, 0);
    // ph4: Q(1,1)@buf0 ; vmcnt(4) publishes buf1/t1 ; issue Q(0,0)@buf1
    STAGE_A(0,0,t2);
    VMCNT4();
    BAR();
    LDA_TO(afX, 1, 0);
    LDB_TO(bfX, 1, 0);
    LGKMW(12);
    MFMA_Q(afY, bfY, 1, 1);
    // ph5: Q(0,0)@buf1 ; issue bfN1@buf1
    STAGE_A(0,1,t2);
    BAR();
    LDB_TO(bfY, 1, 1);
    LGKMW(4);
    MFMA_Q(afX, bfX, 0, 0);
    // ph6: Q(0,1)@buf1 ; issue afG1@buf1
    STAGE_B(0,1,t2);
    BAR();
    LDA_TO(afY, 1, 1);
    LGKMW(8);
    MFMA_Q(afX, bfY, 0, 1);
    // ph7: Q(1,0)@buf1
    STAGE_B(1,0,t3);
    BAR();
    LGKMW(0);
    MFMA_Q(afY, bfX, 1, 0);
    // ph8: Q(1,1)@buf1 ; vmcnt(4) publishes buf0/t2 ; issue Q(0,0)@buf0
    STAGE_A(1,0,t3);
    VMCNT4();
    BAR();
    LDA_TO(afX, 0, 0);
    LDB_TO(bfX, 0, 0);
    LGKMW(12);
    MFMA_Q(afY, bfY, 1, 1);
  }

  // ---- peeled tail (tiles 62,63): ph4 full-drains (r4 under-retire fix) ----
  {
    const int t1 = NTILE-1;   // 63
    // ph1
    STAGE_A(1,1,t1);
    BAR();
    LDB_TO(bfY, 0, 1);
    LGKMW(4);
    MFMA_Q(afX, bfX, 0, 0);
    // ph2
    STAGE_B(1,1,t1);
    BAR();
    LDA_TO(afY, 0, 1);
    LGKMW(8);
    MFMA_Q(afX, bfY, 0, 1);
    // ph3
    BAR();
    LGKMW(0);
    MFMA_Q(afY, bfX, 1, 0);
    // ph4: FULL drain -> all of buf1/t63 published ; issue Q(0,0)@buf1
    VMCNT0();
    BAR();
    LDA_TO(afX, 1, 0);
    LDB_TO(bfX, 1, 0);
    LGKMW(12);
    MFMA_Q(afY, bfY, 1, 1);
    // ph5
    BAR();
    LDB_TO(bfY, 1, 1);
    LGKMW(4);
    MFMA_Q(afX, bfX, 0, 0);
    // ph6
    BAR();
    LDA_TO(afY, 1, 1);
    LGKMW(8);
    MFMA_Q(afX, bfY, 0, 1);
    // ph7
    BAR();
    LGKMW(0);
    MFMA_Q(afY, bfX, 1, 0);
    // ph8
    LGKMW(0);
    MFMA_Q(afY, bfY, 1, 1);
  }

  // ---- epilogue: C/D layout col=lane&15, row=(lane>>4)*4+i ----
  const int cl = lane & 15;
  const int rq = (lane >> 4) << 2;
  #pragma unroll
  for (int nf=0; nf<4; ++nf){
    int col = bcol + wn*64 + nf*16 + cl;
    float bvs = g_bias[col];
    #pragma unroll
    for (int mf=0; mf<8; ++mf){
      int row = brow + wm*128 + mf*16 + rq;
      f32x4 v = acc[mf][nf];
      #pragma unroll
      for (int i=0;i<4;++i)
        Y[(size_t)(row+i)*N_DIM + col] = v[i] + bvs;
    }
  }
}

// ============== fallback 128x128 dbuf GEMM (paths B/C, proven r2) ==============
template<bool PRE_A, bool PRE_B>
__global__ __launch_bounds__(256, 2)
void qgemm(const ushort_t* __restrict__ Xb, const float* __restrict__ Xf,
           const ushort_t* __restrict__ Wb, const int* __restrict__ Wq,
           const float* __restrict__ g_scale, const float* __restrict__ g_zp,
           const float* __restrict__ g_bias, float* __restrict__ Y)
{
  const int BM=128, BK=64, NT=K_DIM/BK, GRID_N=N_DIM/128, NWG=(M_DIM/128)*GRID_N;
  __shared__ __align__(16) ushort_t As[2][BM*BK];
  __shared__ __align__(16) ushort_t Bs[2][BM*BK];

  const int t = threadIdx.x, lane = t & 63, w = t >> 6;
  const int wr = w >> 1, wc = w & 1;
  int bid = blockIdx.x;
  int swz = (bid & 7) * (NWG/8) + (bid >> 3);
  int by = swz / GRID_N, bx = swz - by*GRID_N;
  const int brow = by*128, bcol = bx*128;

  f32x4 acc[4][4] = {};
  const int s8 = t & 7, r0 = t >> 3;
  const int g_r = lane >> 3, g_s = (lane & 7) ^ g_r;

  float wsc[4], wof[4];
  if constexpr (!PRE_B){
    #pragma unroll
    for (int i=0;i<4;++i){
      int n = bcol + r0 + 32*i;
      float sc = g_scale[n];
      wsc[i] = sc; wof[i] = -g_zp[n]*sc;
    }
  }
  float4 ax[4][2]; int4 bq[4][2];
  auto loadA = [&](int kt){
    #pragma unroll
    for (int i=0;i<4;++i){
      const float* p = Xf + (size_t)(brow + r0 + 32*i)*K_DIM + kt*BK + s8*8;
      ax[i][0] = *(const float4*)p; ax[i][1] = *(const float4*)(p+4);
    }};
  auto loadB = [&](int kt){
    #pragma unroll
    for (int i=0;i<4;++i){
      const int* p = Wq + (size_t)(bcol + r0 + 32*i)*K_DIM + kt*BK + s8*8;
      bq[i][0] = *(const int4*)p; bq[i][1] = *(const int4*)(p+4);
    }};
  auto stageA_gll = [&](int buf, int kt){
    #pragma unroll
    for (int i=0;i<4;++i){ int c = w*4 + i;
      gll16(Xb + (size_t)(brow + 8*c + g_r)*K_DIM + kt*BK + g_s*8, &As[buf][c*512]); }};
  auto stageB_gll = [&](int buf, int kt){
    #pragma unroll
    for (int i=0;i<4;++i){ int c = w*4 + i;
      gll16(Wb + (size_t)(bcol + 8*c + g_r)*K_DIM + kt*BK + g_s*8, &Bs[buf][c*512]); }};
  auto stageA_reg = [&](int buf){
    #pragma unroll
    for (int i=0;i<4;++i){
      short8 o;
      o[0]=(short)f2bf(ax[i][0].x); o[1]=(short)f2bf(ax[i][0].y);
      o[2]=(short)f2bf(ax[i][0].z); o[3]=(short)f2bf(ax[i][0].w);
      o[4]=(short)f2bf(ax[i][1].x); o[5]=(short)f2bf(ax[i][1].y);
      o[6]=(short)f2bf(ax[i][1].z); o[7]=(short)f2bf(ax[i][1].w);
      int r = r0 + 32*i; int idx = (r*BK + s8*8) ^ ((r&7)<<3);
      *(short8*)&As[buf][idx] = o; }};
  auto stageB_reg = [&](int buf){
    #pragma unroll
    for (int i=0;i<4;++i){
      short8 o;
      o[0]=(short)f2bf((float)bq[i][0].x*wsc[i]+wof[i]);
      o[1]=(short)f2bf((float)bq[i][0].y*wsc[i]+wof[i]);
      o[2]=(short)f2bf((float)bq[i][0].z*wsc[i]+wof[i]);
      o[3]=(short)f2bf((float)bq[i][0].w*wsc[i]+wof[i]);
      o[4]=(short)f2bf((float)bq[i][1].x*wsc[i]+wof[i]);
      o[5]=(short)f2bf((float)bq[i][1].y*wsc[i]+wof[i]);
      o[6]=(short)f2bf((float)bq[i][1].z*wsc[i]+wof[i]);
      o[7]=(short)f2bf((float)bq[i][1].w*wsc[i]+wof[i]);
      int r = r0 + 32*i; int idx = (r*BK + s8*8) ^ ((r&7)<<3);
      *(short8*)&Bs[buf][idx] = o; }};

  if constexpr (!PRE_A) loadA(0);
  if constexpr (!PRE_B) loadB(0);
  if constexpr (PRE_A) stageA_gll(0,0); else stageA_reg(0);
  if constexpr (PRE_B) stageB_gll(0,0); else stageB_reg(0);
  if constexpr (!PRE_A) { if (NT > 1) loadA(1); }
  if constexpr (!PRE_B) { if (NT > 1) loadB(1); }

  int cur = 0;
  for (int kt=0; kt<NT; ++kt){
    asm volatile("s_waitcnt vmcnt(0) lgkmcnt(0)" ::: "memory");
    __builtin_amdgcn_sched_barrier(0);
    __syncthreads();
    const int nxt = cur ^ 1;
    if (kt+1 < NT){
      if constexpr (PRE_A) stageA_gll(nxt, kt+1); else stageA_reg(nxt);
      if constexpr (PRE_B) stageB_gll(nxt, kt+1); else stageB_reg(nxt);
      if constexpr (!PRE_A) { if (kt+2 < NT) loadA(kt+2); }
      if constexpr (!PRE_B) { if (kt+2 < NT) loadB(kt+2); }
    }
    const ushort_t* as = As[cur];
    const ushort_t* bs = Bs[cur];
    #pragma unroll
    for (int kk=0; kk<2; ++kk){
      bf16x8 af[4], bfr[4];
      const int klo = kk*32 + ((lane>>4)<<3);
      #pragma unroll
      for (int mf=0; mf<4; ++mf){
        int r = wr*64 + mf*16 + (lane&15);
        af[mf] = *(const bf16x8*)&as[(r*BK + klo) ^ ((r&7)<<3)];
      }
      #pragma unroll
      for (int nf=0; nf<4; ++nf){
        int r = wc*64 + nf*16 + (lane&15);
        bfr[nf] = *(const bf16x8*)&bs[(r*BK + klo) ^ ((r&7)<<3)];
      }
      #pragma unroll
      for (int mf=0; mf<4; ++mf)
        #pragma unroll
        for (int nf=0; nf<4; ++nf)
          acc[mf][nf] = __builtin_amdgcn_mfma_f32_16x16x32_bf16(af[mf], bfr[nf], acc[mf][nf], 0,0,0);
    }
    cur = nxt;
  }
  const int cl = lane & 15, rq = (lane >> 4) << 2;
  #pragma unroll
  for (int nf=0; nf<4; ++nf){
    int col = bcol + wc*64 + nf*16 + cl;
    float bvs = g_bias[col];
    #pragma unroll
    for (int mf=0; mf<4; ++mf){
      int row = brow + wr*64 + mf*16 + rq;
      f32x4 v = acc[mf][nf];
      #pragma unroll
      for (int i=0;i<4;++i)
        Y[(size_t)(row+i)*N_DIM + col] = v[i] + bvs;
    }
  }
}

// ---------------- launch ----------------
extern "C" void kernel_launch(void* const* d_in, const int* in_sizes, int n_in,
                              void* d_out, int out_size, void* d_ws, size_t ws_size,
                              hipStream_t stream) {
  const float* x     = (const float*)d_in[0];
  const int*   qw    = (const int*)  d_in[1];
  const float* scale = (const float*)d_in[2];
  const float* zp    = (const float*)d_in[3];
  const float* bias  = (const float*)d_in[4];
  float* y = (float*)d_out;

  const size_t XB = (size_t)M_DIM*K_DIM*2;
  const size_t WB = (size_t)N_DIM*K_DIM*2;

  if (ws_size >= XB + WB){
    ushort_t* xb = (ushort_t*)d_ws;
    ushort_t* wb = (ushort_t*)((char*)d_ws + XB);
    cvt_x_kernel<<<2048, 256, 0, stream>>>(x, xb);
    cvt_w_kernel<<<2048, 256, 0, stream>>>(qw, scale, zp, wb);
    qgemm256<<<dim3((M_DIM/256)*(N_DIM/256)), dim3(512), 0, stream>>>(xb, wb, bias, y);
  } else if (ws_size >= WB){
    ushort_t* wb = (ushort_t*)d_ws;
    cvt_w_kernel<<<2048, 256, 0, stream>>>(qw, scale, zp, wb);
    qgemm<false,true><<<dim3((M_DIM/128)*(N_DIM/128)), dim3(256), 0, stream>>>(nullptr, x, wb, nullptr, scale, zp, bias, y);
  } else {
    qgemm<false,false><<<dim3((M_DIM/128)*(N_DIM/128)), dim3(256), 0, stream>>>(nullptr, x, nullptr, qw, scale, zp, bias, y);
  }
}

// Round 15
// 572.314 us; speedup vs baseline: 2.2745x; 2.2745x over previous
//
#include <hip/hip_runtime.h>
#include <hip/hip_bf16.h>
#include <stdint.h>

// ---------------- problem constants ----------------
#define M_DIM 8192            // B*S = 4*2048
#define N_DIM 11008
#define K_DIM 4096
#define NTILE 64              // K-tiles of 64

typedef unsigned short ushort_t;
typedef __attribute__((ext_vector_type(8)))  short  short8;
typedef __attribute__((ext_vector_type(8)))  __bf16 bf16x8;
typedef __attribute__((ext_vector_type(4)))  float  f32x4;
typedef __attribute__((ext_vector_type(4)))  int    i32x4;
typedef __attribute__((ext_vector_type(16))) char   char16;

__device__ __forceinline__ ushort_t f2bf(float f){
  uint32_t u = __builtin_bit_cast(uint32_t, f);
  u += 0x7FFFu + ((u >> 16) & 1u);
  return (ushort_t)(u >> 16);
}

__device__ __forceinline__ void gll16(const void* g, void* l){
  __builtin_amdgcn_global_load_lds(
      (const __attribute__((address_space(1))) void*)g,
      (__attribute__((address_space(3))) void*)l,
      16, 0, 0);
}

// ---------------- pre-pass: per-row int8 quantization of X ----------------
// x[row] -> xq int8 (sx = rowmax/127), sxv[row] = sx, sxs[row] = sum(xq) (exact)
__global__ __launch_bounds__(256)
void quant_x(const float* __restrict__ x, signed char* __restrict__ xq,
             float* __restrict__ sxv, float* __restrict__ sxs){
  const int row  = blockIdx.x;
  const int t    = threadIdx.x;
  const int lane = t & 63, wid = t >> 6;
  const float* xr = x + (size_t)row * K_DIM;

  float e[16];
  {
    const float4* p = (const float4*)(xr + t*16);
    float4 v0 = p[0], v1 = p[1], v2 = p[2], v3 = p[3];
    e[0]=v0.x; e[1]=v0.y; e[2]=v0.z; e[3]=v0.w;
    e[4]=v1.x; e[5]=v1.y; e[6]=v1.z; e[7]=v1.w;
    e[8]=v2.x; e[9]=v2.y; e[10]=v2.z; e[11]=v2.w;
    e[12]=v3.x; e[13]=v3.y; e[14]=v3.z; e[15]=v3.w;
  }
  float am = 0.f;
  #pragma unroll
  for (int j=0;j<16;++j) am = fmaxf(am, fabsf(e[j]));
  #pragma unroll
  for (int off=32; off; off>>=1) am = fmaxf(am, __shfl_xor(am, off));

  __shared__ float sm[4];
  __shared__ float ss[4];
  if (lane == 0) sm[wid] = am;
  __syncthreads();
  const float amax = fmaxf(fmaxf(sm[0],sm[1]), fmaxf(sm[2],sm[3]));
  const float inv = amax > 0.f ? 127.f/amax : 0.f;
  const float sx  = amax > 0.f ? amax*(1.f/127.f) : 1.f;

  char16 c;
  float fs = 0.f;
  #pragma unroll
  for (int j=0;j<16;++j){
    float r = rintf(e[j]*inv);      // |r| <= 127
    fs += r;
    c[j] = (signed char)(int)r;
  }
  *(char16*)(xq + (size_t)row*K_DIM + t*16) = c;

  #pragma unroll
  for (int off=32; off; off>>=1) fs += __shfl_xor(fs, off);
  if (lane == 0) ss[wid] = fs;
  __syncthreads();
  if (t == 0){
    sxv[row] = sx;
    sxs[row] = ss[0]+ss[1]+ss[2]+ss[3];   // integer-valued, exact in f32
  }
}

// ---------------- pre-pass: W int32 -> int8 (q - 128, signed) ----------------
__global__ void cvt_w8(const int* __restrict__ q, signed char* __restrict__ wq){
  const int TOT = (int)((size_t)N_DIM*K_DIM/16);   // 2,818,048
  for (int c = blockIdx.x*blockDim.x + threadIdx.x; c < TOT; c += gridDim.x*blockDim.x){
    size_t i = (size_t)c*16;
    int4 a = *(const int4*)(q+i);
    int4 b = *(const int4*)(q+i+4);
    int4 d = *(const int4*)(q+i+8);
    int4 f = *(const int4*)(q+i+12);
    char16 o;
    o[0]=(signed char)(a.x-128);  o[1]=(signed char)(a.y-128);
    o[2]=(signed char)(a.z-128);  o[3]=(signed char)(a.w-128);
    o[4]=(signed char)(b.x-128);  o[5]=(signed char)(b.y-128);
    o[6]=(signed char)(b.z-128);  o[7]=(signed char)(b.w-128);
    o[8]=(signed char)(d.x-128);  o[9]=(signed char)(d.y-128);
    o[10]=(signed char)(d.z-128); o[11]=(signed char)(d.w-128);
    o[12]=(signed char)(f.x-128); o[13]=(signed char)(f.y-128);
    o[14]=(signed char)(f.z-128); o[15]=(signed char)(f.w-128);
    *(char16*)(wq+i) = o;
  }
}

// ====== 256x256 int8 GEMM, mfma_i32_16x16x64_i8, r9 skeleton (r11) ======
// Feed-bound diagnosis: r3/r6/r9 all ~6050 cyc/K-tile = 64KB staged at the
// ~6.5 TB/s L3-feed ceiling. int8 halves staged bytes (32KB/K-tile), halves
// LDS reads, and halves MFMA time (K=64/instr, int32-exact accumulate).
// y = s_n*sx_m*IQ' + sx_m*SX_m*s_n*(128-zp_n) + b_n  (wq' = q-128).
// Schedule = r9 (proven, replay-stable): 8 phases/2 K-tiles, same-phase
// reads before barrier + lgkm0 after, counted vmcnt (1 gll per stage now):
//   steady: 8 outstanding at ph4 -> vmcnt(2) retires all 4 of buf1/t1;
//           6 at ph8 -> vmcnt(2) retires all 4 of buf0/t2; never 0.
//   prologue: 6 staged, vmcnt(2) retires buf0's 4.
//   peeled tail: ph4 vmcnt(0) (counted wait under-retires when t2/t3 absent).
// LDS: A,B tiles 256x64 int8 as 2 halves of [128][64], dbuf = 64 KB.
// Swizzle (64B rows, r8-verified): LDS[row][s16] = G[row][s16 ^ ((row>>1)&3)];
// residual 2-way conflict is free (m136).

#define BAR() do{ asm volatile("" ::: "memory"); \
  __builtin_amdgcn_s_barrier(); \
  asm volatile("" ::: "memory"); }while(0)

#define LGKM0() asm volatile("s_waitcnt lgkmcnt(0)" ::: "memory")

#define VMW2() do{ __builtin_amdgcn_sched_barrier(0); \
  asm volatile("s_waitcnt vmcnt(2)" ::: "memory"); \
  __builtin_amdgcn_sched_barrier(0); }while(0)

#define VMW0() do{ __builtin_amdgcn_sched_barrier(0); \
  asm volatile("s_waitcnt vmcnt(0)" ::: "memory"); \
  __builtin_amdgcn_sched_barrier(0); }while(0)

// A fragments: group G (0/1) = m-frags G*4..G*4+3; 16B per lane (K=64)
#define LDA_TO(DST, BUF, G) do{ \
  const signed char* _b = &As[BUF][wm][0]; \
  _Pragma("unroll") for (int mf=0; mf<4; ++mf) \
    DST[mf] = *(const i32x4*)(_b + ((G)*64 + mf*16 + rl)*64 + offk); \
}while(0)

// B fragments: group NG (0/1) = n-frags NG*2..NG*2+1 within the wave's 64 cols
#define LDB_TO(DST, BUF, NG) do{ \
  const signed char* _b = &Bs[BUF][hb][0]; \
  _Pragma("unroll") for (int nfl=0; nfl<2; ++nfl) \
    DST[nfl] = *(const i32x4*)(_b + (hbr + (NG)*32 + nfl*16 + rl)*64 + offk); \
}while(0)

#define MM_Q(AF, BF, MG, NG) do{ \
  __builtin_amdgcn_s_setprio(1); \
  _Pragma("unroll") for (int mf=0; mf<4; ++mf) \
    _Pragma("unroll") for (int nfl=0; nfl<2; ++nfl) \
      acc[(MG)*4+mf][(NG)*2+nfl] = __builtin_amdgcn_mfma_i32_16x16x64_i8( \
          AF[mf], BF[nfl], acc[(MG)*4+mf][(NG)*2+nfl], 0, 0, 0); \
  __builtin_amdgcn_s_setprio(0); \
}while(0)

// one gll16 per wave per half-tile (8 waves x 1KB = 8KB = 128 rows x 64B)
#define STAGE_A(BUF, H, T) gll16(aS[H] + (size_t)(T)*64, &As[BUF][H][w*1024])
#define STAGE_B(BUF, H, T) gll16(bS[H] + (size_t)(T)*64, &Bs[BUF][H][w*1024])

__global__ __launch_bounds__(512, 1)
void qgemm256_i8(const signed char* __restrict__ Xq, const signed char* __restrict__ Wq,
                 const float* __restrict__ g_scale, const float* __restrict__ g_zp,
                 const float* __restrict__ g_bias,
                 const float* __restrict__ sxv, const float* __restrict__ sxs,
                 float* __restrict__ Y)
{
  __shared__ __align__(16) signed char As[2][2][8192];   // 32 KB
  __shared__ __align__(16) signed char Bs[2][2][8192];   // 32 KB

  const int t    = threadIdx.x;
  const int lane = t & 63;
  const int w    = t >> 6;        // 0..7
  const int wm   = w >> 2;        // 0..1  (M half)
  const int wn   = w & 3;         // 0..3  (N quarter)
  const int hb   = wn >> 1;       // B half
  const int hbr  = (wn & 1) * 64; // row base within B half

  const int GM2 = M_DIM/256, GN2 = N_DIM/256;   // 32, 43
  const int NWG2 = GM2*GN2;                      // 1376 (%8==0)
  int bid = blockIdx.x;
  int swz = (bid & 7) * (NWG2/8) + (bid >> 3);
  int by = swz / GN2, bx = swz - by*GN2;
  const int brow = by*256, bcol = bx*256;

  // fragment-read lane constants: row = <frag>*16 + rl, 16B at swizzled slot
  const int rl   = lane & 15;
  const int offk = ((lane >> 4) ^ ((rl >> 1) & 3)) * 16;   // bytes

  // staging: wave w stages rows w*16..w*16+15 of each 128-row half.
  // lane l -> row l>>2, slot l&3; source pre-swizzled so LDS lands swizzled.
  const int g_s = (lane & 3) ^ ((lane >> 3) & 3);
  const signed char* aS[2];
  const signed char* bS[2];
  #pragma unroll
  for (int h=0; h<2; ++h){
    int r = h*128 + w*16 + (lane >> 2);
    aS[h] = Xq + (size_t)(brow + r)*K_DIM + g_s*16;
    bS[h] = Wq + (size_t)(bcol + r)*K_DIM + g_s*16;
  }

  i32x4 acc[8][4] = {};
  i32x4 afX[4], afY[4];    // A frags: G0 / G1 (16 regs each... 16 total each)
  i32x4 bfX[2], bfY[2];    // B frags: NG0 / NG1

  // ---- prologue: buf0 <- tile0 (4 halves), buf1 <- tile1 (B.h0, A.h0) ----
  STAGE_B(0,0,0); STAGE_A(0,0,0); STAGE_A(0,1,0); STAGE_B(0,1,0);
  STAGE_B(1,0,1); STAGE_A(1,0,1);
  VMW2();                 // retire buf0's 4; buf1's 2 stay in flight
  BAR();

  #pragma unroll 1
  for (int j=0; j<NTILE/2-1; ++j){      // j = 0..30
    const int t1 = 2*j+1, t2 = 2*j+2, t3 = 2*j+3;
    // ph1: reads Q(0,0)@buf0 | stage A[b1].h1 <- t1
    LDA_TO(afX, 0, 0);
    LDB_TO(bfX, 0, 0);
    STAGE_A(1,1,t1);
    BAR(); LGKM0();
    MM_Q(afX, bfX, 0, 0);
    BAR();
    // ph2: reads B.N1@buf0 | stage B[b1].h1 <- t1
    LDB_TO(bfY, 0, 1);
    STAGE_B(1,1,t1);
    BAR(); LGKM0();
    MM_Q(afX, bfY, 0, 1);
    BAR();
    // ph3: reads A.G1@buf0 | stage B[b0].h0 <- t2
    LDA_TO(afY, 0, 1);
    STAGE_B(0,0,t2);
    BAR(); LGKM0();
    MM_Q(afY, bfX, 1, 0);
    BAR();
    // ph4: stage A[b0].h0 <- t2 | vmcnt(2): buf1/t1 fully published
    STAGE_A(0,0,t2);
    VMW2();
    BAR();
    MM_Q(afY, bfY, 1, 1);
    BAR();
    // ph5: reads Q(0,0)@buf1 | stage A[b0].h1 <- t2
    LDA_TO(afX, 1, 0);
    LDB_TO(bfX, 1, 0);
    STAGE_A(0,1,t2);
    BAR(); LGKM0();
    MM_Q(afX, bfX, 0, 0);
    BAR();
    // ph6: reads B.N1@buf1 | stage B[b0].h1 <- t2
    LDB_TO(bfY, 1, 1);
    STAGE_B(0,1,t2);
    BAR(); LGKM0();
    MM_Q(afX, bfY, 0, 1);
    BAR();
    // ph7: reads A.G1@buf1 | stage B[b1].h0 <- t3
    LDA_TO(afY, 1, 1);
    STAGE_B(1,0,t3);
    BAR(); LGKM0();
    MM_Q(afY, bfX, 1, 0);
    BAR();
    // ph8: stage A[b1].h0 <- t3 | vmcnt(2): buf0/t2 fully published
    STAGE_A(1,0,t3);
    VMW2();
    BAR();
    MM_Q(afY, bfY, 1, 1);
    BAR();
  }

  // ---- peeled tail (tiles 62,63): ph4 full-drains (r4 under-retire fix) ----
  {
    const int t1 = NTILE-1;   // 63
    LDA_TO(afX, 0, 0);
    LDB_TO(bfX, 0, 0);
    STAGE_A(1,1,t1);
    BAR(); LGKM0();
    MM_Q(afX, bfX, 0, 0);
    BAR();
    LDB_TO(bfY, 0, 1);
    STAGE_B(1,1,t1);
    BAR(); LGKM0();
    MM_Q(afX, bfY, 0, 1);
    BAR();
    LDA_TO(afY, 0, 1);
    BAR(); LGKM0();
    MM_Q(afY, bfX, 1, 0);
    BAR();
    VMW0();                         // all of buf1/t63 published
    BAR();
    MM_Q(afY, bfY, 1, 1);
    BAR();
    LDA_TO(afX, 1, 0);
    LDB_TO(bfX, 1, 0);
    BAR(); LGKM0();
    MM_Q(afX, bfX, 0, 0);
    BAR();
    LDB_TO(bfY, 1, 1);
    BAR(); LGKM0();
    MM_Q(afX, bfY, 0, 1);
    BAR();
    LDA_TO(afY, 1, 1);
    BAR(); LGKM0();
    MM_Q(afY, bfX, 1, 0);
    BAR();
    MM_Q(afY, bfY, 1, 1);
  }

  // ---- epilogue: C/D col=lane&15, row=(lane>>4)*4+i (shape-determined) ----
  // y = IQ'*(s_n*sx_m) + sx_m*SX_m*(s_n*(128-zp_n)) + b_n
  const int cl = lane & 15;
  const int rq = (lane >> 4) << 2;
  float sN[4], cN[4], bN[4];
  #pragma unroll
  for (int nf=0; nf<4; ++nf){
    int col = bcol + wn*64 + nf*16 + cl;
    float s = g_scale[col];
    sN[nf] = s;
    cN[nf] = s * (128.f - g_zp[col]);
    bN[nf] = g_bias[col];
  }
  #pragma unroll
  for (int mf=0; mf<8; ++mf){
    const int rowb = brow + wm*128 + mf*16 + rq;
    float sx0 = sxv[rowb],   sx1 = sxv[rowb+1], sx2 = sxv[rowb+2], sx3 = sxv[rowb+3];
    float t0 = sx0*sxs[rowb],   t1 = sx1*sxs[rowb+1];
    float t2 = sx2*sxs[rowb+2], t3 = sx3*sxs[rowb+3];
    #pragma unroll
    for (int nf=0; nf<4; ++nf){
      int col = bcol + wn*64 + nf*16 + cl;
      size_t base = (size_t)rowb*N_DIM + col;
      i32x4 v = acc[mf][nf];
      Y[base            ] = (float)v[0]*(sN[nf]*sx0) + t0*cN[nf] + bN[nf];
      Y[base +   N_DIM  ] = (float)v[1]*(sN[nf]*sx1) + t1*cN[nf] + bN[nf];
      Y[base + 2*N_DIM  ] = (float)v[2]*(sN[nf]*sx2) + t2*cN[nf] + bN[nf];
      Y[base + 3*N_DIM  ] = (float)v[3]*(sN[nf]*sx3) + t3*cN[nf] + bN[nf];
    }
  }
}

// ============== fallback 128x128 conv GEMM (ws too small; r2-proven) ==============
__global__ __launch_bounds__(256, 2)
void qgemm_fb(const float* __restrict__ Xf, const int* __restrict__ Wq,
              const float* __restrict__ g_scale, const float* __restrict__ g_zp,
              const float* __restrict__ g_bias, float* __restrict__ Y)
{
  const int BM=128, BK=64, NT=K_DIM/BK, GRID_N=N_DIM/128, NWG=(M_DIM/128)*GRID_N;
  __shared__ __align__(16) ushort_t As[2][BM*BK];
  __shared__ __align__(16) ushort_t Bs[2][BM*BK];

  const int t = threadIdx.x, lane = t & 63, w = t >> 6;
  const int wr = w >> 1, wc = w & 1;
  int bid = blockIdx.x;
  int swz = (bid & 7) * (NWG/8) + (bid >> 3);
  int by = swz / GRID_N, bx = swz - by*GRID_N;
  const int brow = by*128, bcol = bx*128;

  f32x4 acc[4][4] = {};
  const int s8 = t & 7, r0 = t >> 3;

  float wsc[4], wof[4];
  #pragma unroll
  for (int i=0;i<4;++i){
    int n = bcol + r0 + 32*i;
    float sc = g_scale[n];
    wsc[i] = sc; wof[i] = -g_zp[n]*sc;
  }
  float4 ax[4][2]; int4 bq[4][2];
  auto loadA = [&](int kt){
    #pragma unroll
    for (int i=0;i<4;++i){
      const float* p = Xf + (size_t)(brow + r0 + 32*i)*K_DIM + kt*BK + s8*8;
      ax[i][0] = *(const float4*)p; ax[i][1] = *(const float4*)(p+4);
    }};
  auto loadB = [&](int kt){
    #pragma unroll
    for (int i=0;i<4;++i){
      const int* p = Wq + (size_t)(bcol + r0 + 32*i)*K_DIM + kt*BK + s8*8;
      bq[i][0] = *(const int4*)p; bq[i][1] = *(const int4*)(p+4);
    }};
  auto stageA = [&](int buf){
    #pragma unroll
    for (int i=0;i<4;++i){
      short8 o;
      o[0]=(short)f2bf(ax[i][0].x); o[1]=(short)f2bf(ax[i][0].y);
      o[2]=(short)f2bf(ax[i][0].z); o[3]=(short)f2bf(ax[i][0].w);
      o[4]=(short)f2bf(ax[i][1].x); o[5]=(short)f2bf(ax[i][1].y);
      o[6]=(short)f2bf(ax[i][1].z); o[7]=(short)f2bf(ax[i][1].w);
      int r = r0 + 32*i; int idx = (r*BK + s8*8) ^ ((r&7)<<3);
      *(short8*)&As[buf][idx] = o; }};
  auto stageB = [&](int buf){
    #pragma unroll
    for (int i=0;i<4;++i){
      short8 o;
      o[0]=(short)f2bf((float)bq[i][0].x*wsc[i]+wof[i]);
      o[1]=(short)f2bf((float)bq[i][0].y*wsc[i]+wof[i]);
      o[2]=(short)f2bf((float)bq[i][0].z*wsc[i]+wof[i]);
      o[3]=(short)f2bf((float)bq[i][0].w*wsc[i]+wof[i]);
      o[4]=(short)f2bf((float)bq[i][1].x*wsc[i]+wof[i]);
      o[5]=(short)f2bf((float)bq[i][1].y*wsc[i]+wof[i]);
      o[6]=(short)f2bf((float)bq[i][1].z*wsc[i]+wof[i]);
      o[7]=(short)f2bf((float)bq[i][1].w*wsc[i]+wof[i]);
      int r = r0 + 32*i; int idx = (r*BK + s8*8) ^ ((r&7)<<3);
      *(short8*)&Bs[buf][idx] = o; }};

  loadA(0); loadB(0);
  stageA(0); stageB(0);
  if (NT > 1){ loadA(1); loadB(1); }

  int cur = 0;
  for (int kt=0; kt<NT; ++kt){
    asm volatile("s_waitcnt vmcnt(0) lgkmcnt(0)" ::: "memory");
    __builtin_amdgcn_sched_barrier(0);
    __syncthreads();
    const int nxt = cur ^ 1;
    if (kt+1 < NT){
      stageA(nxt); stageB(nxt);
      if (kt+2 < NT){ loadA(kt+2); loadB(kt+2); }
    }
    const ushort_t* as = As[cur];
    const ushort_t* bs = Bs[cur];
    #pragma unroll
    for (int kk=0; kk<2; ++kk){
      bf16x8 af[4], bfr[4];
      const int klo = kk*32 + ((lane>>4)<<3);
      #pragma unroll
      for (int mf=0; mf<4; ++mf){
        int r = wr*64 + mf*16 + (lane&15);
        af[mf] = *(const bf16x8*)&as[(r*BK + klo) ^ ((r&7)<<3)];
      }
      #pragma unroll
      for (int nf=0; nf<4; ++nf){
        int r = wc*64 + nf*16 + (lane&15);
        bfr[nf] = *(const bf16x8*)&bs[(r*BK + klo) ^ ((r&7)<<3)];
      }
      #pragma unroll
      for (int mf=0; mf<4; ++mf)
        #pragma unroll
        for (int nf=0; nf<4; ++nf)
          acc[mf][nf] = __builtin_amdgcn_mfma_f32_16x16x32_bf16(af[mf], bfr[nf], acc[mf][nf], 0,0,0);
    }
    cur = nxt;
  }
  const int cl = lane & 15, rq = (lane >> 4) << 2;
  #pragma unroll
  for (int nf=0; nf<4; ++nf){
    int col = bcol + wc*64 + nf*16 + cl;
    float bvs = g_bias[col];
    #pragma unroll
    for (int mf=0; mf<4; ++mf){
      int row = brow + wr*64 + mf*16 + rq;
      f32x4 v = acc[mf][nf];
      #pragma unroll
      for (int i=0;i<4;++i)
        Y[(size_t)(row+i)*N_DIM + col] = v[i] + bvs;
    }
  }
}

// ---------------- launch ----------------
extern "C" void kernel_launch(void* const* d_in, const int* in_sizes, int n_in,
                              void* d_out, int out_size, void* d_ws, size_t ws_size,
                              hipStream_t stream) {
  const float* x     = (const float*)d_in[0];
  const int*   qw    = (const int*)  d_in[1];
  const float* scale = (const float*)d_in[2];
  const float* zp    = (const float*)d_in[3];
  const float* bias  = (const float*)d_in[4];
  float* y = (float*)d_out;

  const size_t XQ = (size_t)M_DIM*K_DIM;        // 33,554,432 (int8)
  const size_t WQ = (size_t)N_DIM*K_DIM;        // 45,088,768 (int8)
  const size_t SV = (size_t)M_DIM*4;            // 32 KB
  const size_t need = XQ + WQ + 2*SV;

  if (ws_size >= need){
    signed char* xq = (signed char*)d_ws;
    signed char* wq = (signed char*)d_ws + XQ;
    float* sxv = (float*)((char*)d_ws + XQ + WQ);
    float* sxs = sxv + M_DIM;
    quant_x<<<dim3(M_DIM), dim3(256), 0, stream>>>(x, xq, sxv, sxs);
    cvt_w8<<<dim3(2048), dim3(256), 0, stream>>>(qw, wq);
    qgemm256_i8<<<dim3((M_DIM/256)*(N_DIM/256)), dim3(512), 0, stream>>>(
        xq, wq, scale, zp, bias, sxv, sxs, y);
  } else {
    qgemm_fb<<<dim3((M_DIM/128)*(N_DIM/128)), dim3(256), 0, stream>>>(
        x, qw, scale, zp, bias, y);
  }
}

// Round 16
// 569.965 us; speedup vs baseline: 2.2838x; 1.0041x over previous
//
#include <hip/hip_runtime.h>
#include <hip/hip_bf16.h>
#include <stdint.h>

// ---------------- problem constants ----------------
#define M_DIM 8192            // B*S = 4*2048
#define N_DIM 11008
#define K_DIM 4096
#define NTILE 64              // K-tiles of 64

typedef unsigned short ushort_t;
typedef __attribute__((ext_vector_type(8)))  short  short8;
typedef __attribute__((ext_vector_type(8)))  __bf16 bf16x8;
typedef __attribute__((ext_vector_type(4)))  float  f32x4;
typedef __attribute__((ext_vector_type(4)))  int    i32x4;
typedef __attribute__((ext_vector_type(16))) char   char16;

__device__ __forceinline__ ushort_t f2bf(float f){
  uint32_t u = __builtin_bit_cast(uint32_t, f);
  u += 0x7FFFu + ((u >> 16) & 1u);
  return (ushort_t)(u >> 16);
}

__device__ __forceinline__ void gll16(const void* g, void* l){
  __builtin_amdgcn_global_load_lds(
      (const __attribute__((address_space(1))) void*)g,
      (__attribute__((address_space(3))) void*)l,
      16, 0, 0);
}

// ---------------- pre-pass: per-row int8 quantization of X ----------------
__global__ __launch_bounds__(256)
void quant_x(const float* __restrict__ x, signed char* __restrict__ xq,
             float* __restrict__ sxv, float* __restrict__ sxs){
  const int row  = blockIdx.x;
  const int t    = threadIdx.x;
  const int lane = t & 63, wid = t >> 6;
  const float* xr = x + (size_t)row * K_DIM;

  float e[16];
  {
    const float4* p = (const float4*)(xr + t*16);
    float4 v0 = p[0], v1 = p[1], v2 = p[2], v3 = p[3];
    e[0]=v0.x; e[1]=v0.y; e[2]=v0.z; e[3]=v0.w;
    e[4]=v1.x; e[5]=v1.y; e[6]=v1.z; e[7]=v1.w;
    e[8]=v2.x; e[9]=v2.y; e[10]=v2.z; e[11]=v2.w;
    e[12]=v3.x; e[13]=v3.y; e[14]=v3.z; e[15]=v3.w;
  }
  float am = 0.f;
  #pragma unroll
  for (int j=0;j<16;++j) am = fmaxf(am, fabsf(e[j]));
  #pragma unroll
  for (int off=32; off; off>>=1) am = fmaxf(am, __shfl_xor(am, off));

  __shared__ float sm[4];
  __shared__ float ss[4];
  if (lane == 0) sm[wid] = am;
  __syncthreads();
  const float amax = fmaxf(fmaxf(sm[0],sm[1]), fmaxf(sm[2],sm[3]));
  const float inv = amax > 0.f ? 127.f/amax : 0.f;
  const float sx  = amax > 0.f ? amax*(1.f/127.f) : 1.f;

  char16 c;
  float fs = 0.f;
  #pragma unroll
  for (int j=0;j<16;++j){
    float r = rintf(e[j]*inv);
    fs += r;
    c[j] = (signed char)(int)r;
  }
  *(char16*)(xq + (size_t)row*K_DIM + t*16) = c;

  #pragma unroll
  for (int off=32; off; off>>=1) fs += __shfl_xor(fs, off);
  if (lane == 0) ss[wid] = fs;
  __syncthreads();
  if (t == 0){
    sxv[row] = sx;
    sxs[row] = ss[0]+ss[1]+ss[2]+ss[3];
  }
}

// ---------------- pre-pass: W int32 -> int8 (q - 128, signed) ----------------
__global__ void cvt_w8(const int* __restrict__ q, signed char* __restrict__ wq){
  const int TOT = (int)((size_t)N_DIM*K_DIM/16);
  for (int c = blockIdx.x*blockDim.x + threadIdx.x; c < TOT; c += gridDim.x*blockDim.x){
    size_t i = (size_t)c*16;
    int4 a = *(const int4*)(q+i);
    int4 b = *(const int4*)(q+i+4);
    int4 d = *(const int4*)(q+i+8);
    int4 f = *(const int4*)(q+i+12);
    char16 o;
    o[0]=(signed char)(a.x-128);  o[1]=(signed char)(a.y-128);
    o[2]=(signed char)(a.z-128);  o[3]=(signed char)(a.w-128);
    o[4]=(signed char)(b.x-128);  o[5]=(signed char)(b.y-128);
    o[6]=(signed char)(b.z-128);  o[7]=(signed char)(b.w-128);
    o[8]=(signed char)(d.x-128);  o[9]=(signed char)(d.y-128);
    o[10]=(signed char)(d.z-128); o[11]=(signed char)(d.w-128);
    o[12]=(signed char)(f.x-128); o[13]=(signed char)(f.y-128);
    o[14]=(signed char)(f.z-128); o[15]=(signed char)(f.w-128);
    *(char16*)(wq+i) = o;
  }
}

// == 256x256 int8 GEMM, one-ahead reads + counted lgkm (r12) ==
// Phase p: PRE{reads for MFMA p+1 | stage | [vmcnt]} BAR
//          POST{[buf-opening reads], LGKMW(N=issued this window), MFMA p} BAR
// MFMA p's operands issued in phase p-1 -> landed by LGKMW; phase p's read
// burst drains UNDER MFMA p (the r11 serialization removed).
// Safety (verified window-by-window):
//  WAR: reads issued window p complete by wave's LGKMW in window p+1 (before
//       its MFMA and BAR_close); every conflicting stage is issued >=2
//       windows later (ph-map: A0 reads ph8/ph2 vs stages ph4/ph5; B0 ph8/ph1
//       vs ph3/ph6; A1 ph4/ph6 vs ph8/ph1'; B1 ph4/ph5 vs ph7/ph2').
//  RAW-DMA: buf-opening reads (afX,bfX) sit in POST of ph4/ph8, AFTER the
//       vmcnt(2)+BAR that retires ALL waves' DMAs to that buffer.
//  vmcnt: steady 6 outstanding at ph4/ph8 -> VMW(2) retires exactly the 4
//       of the buffer being opened; prologue VMW(2); tail ph4 VMW(0).
// LGKMW counts: [2,4,0,6, 2,4,0,6] = reads issued in that window.

#define BAR() do{ asm volatile("" ::: "memory"); \
  __builtin_amdgcn_s_barrier(); \
  asm volatile("" ::: "memory"); }while(0)

#define LGKMW(N) do{ \
  asm volatile("s_waitcnt lgkmcnt(" #N ")" ::: "memory"); \
  __builtin_amdgcn_sched_barrier(0); }while(0)

#define VMW2() do{ __builtin_amdgcn_sched_barrier(0); \
  asm volatile("s_waitcnt vmcnt(2)" ::: "memory"); \
  __builtin_amdgcn_sched_barrier(0); }while(0)

#define VMW0() do{ __builtin_amdgcn_sched_barrier(0); \
  asm volatile("s_waitcnt vmcnt(0)" ::: "memory"); \
  __builtin_amdgcn_sched_barrier(0); }while(0)

#define LDA_TO(DST, BUF, G) do{ \
  const signed char* _b = &As[BUF][wm][0]; \
  _Pragma("unroll") for (int mf=0; mf<4; ++mf) \
    DST[mf] = *(const i32x4*)(_b + ((G)*64 + mf*16 + rl)*64 + offk); \
}while(0)

#define LDB_TO(DST, BUF, NG) do{ \
  const signed char* _b = &Bs[BUF][hb][0]; \
  _Pragma("unroll") for (int nfl=0; nfl<2; ++nfl) \
    DST[nfl] = *(const i32x4*)(_b + (hbr + (NG)*32 + nfl*16 + rl)*64 + offk); \
}while(0)

#define MM_Q(AF, BF, MG, NG) do{ \
  __builtin_amdgcn_s_setprio(1); \
  _Pragma("unroll") for (int mf=0; mf<4; ++mf) \
    _Pragma("unroll") for (int nfl=0; nfl<2; ++nfl) \
      acc[(MG)*4+mf][(NG)*2+nfl] = __builtin_amdgcn_mfma_i32_16x16x64_i8( \
          AF[mf], BF[nfl], acc[(MG)*4+mf][(NG)*2+nfl], 0, 0, 0); \
  __builtin_amdgcn_s_setprio(0); \
}while(0)

#define STAGE_A(BUF, H, T) gll16(aS[H] + (size_t)(T)*64, &As[BUF][H][w*1024])
#define STAGE_B(BUF, H, T) gll16(bS[H] + (size_t)(T)*64, &Bs[BUF][H][w*1024])

__global__ __launch_bounds__(512, 1)
void qgemm256_i8(const signed char* __restrict__ Xq, const signed char* __restrict__ Wq,
                 const float* __restrict__ g_scale, const float* __restrict__ g_zp,
                 const float* __restrict__ g_bias,
                 const float* __restrict__ sxv, const float* __restrict__ sxs,
                 float* __restrict__ Y)
{
  __shared__ __align__(16) signed char As[2][2][8192];   // 32 KB
  __shared__ __align__(16) signed char Bs[2][2][8192];   // 32 KB

  const int t    = threadIdx.x;
  const int lane = t & 63;
  const int w    = t >> 6;        // 0..7
  const int wm   = w >> 2;        // 0..1  (M half)
  const int wn   = w & 3;         // 0..3  (N quarter)
  const int hb   = wn >> 1;       // B half
  const int hbr  = (wn & 1) * 64; // row base within B half

  const int GM2 = M_DIM/256, GN2 = N_DIM/256;   // 32, 43
  const int NWG2 = GM2*GN2;                      // 1376 (%8==0)
  int bid = blockIdx.x;
  int swz = (bid & 7) * (NWG2/8) + (bid >> 3);
  int by = swz / GN2, bx = swz - by*GN2;
  const int brow = by*256, bcol = bx*256;

  const int rl   = lane & 15;
  const int offk = ((lane >> 4) ^ ((rl >> 1) & 3)) * 16;   // bytes

  const int g_s = (lane & 3) ^ ((lane >> 3) & 3);
  const signed char* aS[2];
  const signed char* bS[2];
  #pragma unroll
  for (int h=0; h<2; ++h){
    int r = h*128 + w*16 + (lane >> 2);
    aS[h] = Xq + (size_t)(brow + r)*K_DIM + g_s*16;
    bS[h] = Wq + (size_t)(bcol + r)*K_DIM + g_s*16;
  }

  i32x4 acc[8][4] = {};
  i32x4 afX[4], afY[4];
  i32x4 bfX[2], bfY[2];

  // ---- prologue: buf0 <- tile0 (4 halves), buf1 <- tile1 (B.h0, A.h0) ----
  STAGE_B(0,0,0); STAGE_A(0,0,0); STAGE_A(0,1,0); STAGE_B(0,1,0);
  STAGE_B(1,0,1); STAGE_A(1,0,1);
  VMW2();                 // retire buf0's 4; buf1's 2 stay in flight
  BAR();
  LDA_TO(afX, 0, 0);      // ph1 operands, in flight (landed by POST_ph1 wait)
  LDB_TO(bfX, 0, 0);

  #pragma unroll 1
  for (int j=0; j<NTILE/2-1; ++j){      // j = 0..30
    const int t1 = 2*j+1, t2 = 2*j+2, t3 = 2*j+3;
    // ph1
    LDB_TO(bfY, 0, 1);
    STAGE_A(1,1,t1);
    BAR();
    LGKMW(2);
    MM_Q(afX, bfX, 0, 0);
    BAR();
    // ph2
    LDA_TO(afY, 0, 1);
    STAGE_B(1,1,t1);
    BAR();
    LGKMW(4);
    MM_Q(afX, bfY, 0, 1);
    BAR();
    // ph3
    STAGE_B(0,0,t2);
    BAR();
    LGKMW(0);
    MM_Q(afY, bfX, 1, 0);
    BAR();
    // ph4: vmcnt publishes buf1/t1; open buf1 reads in POST
    STAGE_A(0,0,t2);
    VMW2();
    BAR();
    LDA_TO(afX, 1, 0);
    LDB_TO(bfX, 1, 0);
    LGKMW(6);
    MM_Q(afY, bfY, 1, 1);
    BAR();
    // ph5
    LDB_TO(bfY, 1, 1);
    STAGE_A(0,1,t2);
    BAR();
    LGKMW(2);
    MM_Q(afX, bfX, 0, 0);
    BAR();
    // ph6
    LDA_TO(afY, 1, 1);
    STAGE_B(0,1,t2);
    BAR();
    LGKMW(4);
    MM_Q(afX, bfY, 0, 1);
    BAR();
    // ph7
    STAGE_B(1,0,t3);
    BAR();
    LGKMW(0);
    MM_Q(afY, bfX, 1, 0);
    BAR();
    // ph8: vmcnt publishes buf0/t2; open buf0 reads in POST
    STAGE_A(1,0,t3);
    VMW2();
    BAR();
    LDA_TO(afX, 0, 0);
    LDB_TO(bfX, 0, 0);
    LGKMW(6);
    MM_Q(afY, bfY, 1, 1);
    BAR();
  }

  // ---- peeled tail (tiles 62,63): ph4 full-drains (r4 under-retire fix) ----
  {
    const int t1 = NTILE-1;   // 63
    // ph1
    LDB_TO(bfY, 0, 1);
    STAGE_A(1,1,t1);
    BAR();
    LGKMW(2);
    MM_Q(afX, bfX, 0, 0);
    BAR();
    // ph2
    LDA_TO(afY, 0, 1);
    STAGE_B(1,1,t1);
    BAR();
    LGKMW(4);
    MM_Q(afX, bfY, 0, 1);
    BAR();
    // ph3
    BAR();
    LGKMW(0);
    MM_Q(afY, bfX, 1, 0);
    BAR();
    // ph4: FULL drain -> all of buf1/t63 published; open buf1 reads
    VMW0();
    BAR();
    LDA_TO(afX, 1, 0);
    LDB_TO(bfX, 1, 0);
    LGKMW(6);
    MM_Q(afY, bfY, 1, 1);
    BAR();
    // ph5
    LDB_TO(bfY, 1, 1);
    BAR();
    LGKMW(2);
    MM_Q(afX, bfX, 0, 0);
    BAR();
    // ph6
    LDA_TO(afY, 1, 1);
    BAR();
    LGKMW(4);
    MM_Q(afX, bfY, 0, 1);
    BAR();
    // ph7
    BAR();
    LGKMW(0);
    MM_Q(afY, bfX, 1, 0);
    BAR();
    // ph8
    LGKMW(0);
    MM_Q(afY, bfY, 1, 1);
  }

  // ---- epilogue: C/D col=lane&15, row=(lane>>4)*4+i ----
  // y = IQ'*(s_n*sx_m) + sx_m*SX_m*(s_n*(128-zp_n)) + b_n
  const int cl = lane & 15;
  const int rq = (lane >> 4) << 2;
  float sN[4], cN[4], bN[4];
  #pragma unroll
  for (int nf=0; nf<4; ++nf){
    int col = bcol + wn*64 + nf*16 + cl;
    float s = g_scale[col];
    sN[nf] = s;
    cN[nf] = s * (128.f - g_zp[col]);
    bN[nf] = g_bias[col];
  }
  #pragma unroll
  for (int mf=0; mf<8; ++mf){
    const int rowb = brow + wm*128 + mf*16 + rq;
    float sx0 = sxv[rowb],   sx1 = sxv[rowb+1], sx2 = sxv[rowb+2], sx3 = sxv[rowb+3];
    float t0 = sx0*sxs[rowb],   t1 = sx1*sxs[rowb+1];
    float t2 = sx2*sxs[rowb+2], t3 = sx3*sxs[rowb+3];
    #pragma unroll
    for (int nf=0; nf<4; ++nf){
      int col = bcol + wn*64 + nf*16 + cl;
      size_t base = (size_t)rowb*N_DIM + col;
      i32x4 v = acc[mf][nf];
      Y[base            ] = (float)v[0]*(sN[nf]*sx0) + t0*cN[nf] + bN[nf];
      Y[base +   N_DIM  ] = (float)v[1]*(sN[nf]*sx1) + t1*cN[nf] + bN[nf];
      Y[base + 2*N_DIM  ] = (float)v[2]*(sN[nf]*sx2) + t2*cN[nf] + bN[nf];
      Y[base + 3*N_DIM  ] = (float)v[3]*(sN[nf]*sx3) + t3*cN[nf] + bN[nf];
    }
  }
}

// ============== fallback 128x128 conv GEMM (ws too small; r2-proven) ==============
__global__ __launch_bounds__(256, 2)
void qgemm_fb(const float* __restrict__ Xf, const int* __restrict__ Wq,
              const float* __restrict__ g_scale, const float* __restrict__ g_zp,
              const float* __restrict__ g_bias, float* __restrict__ Y)
{
  const int BM=128, BK=64, NT=K_DIM/BK, GRID_N=N_DIM/128, NWG=(M_DIM/128)*GRID_N;
  __shared__ __align__(16) ushort_t As[2][BM*BK];
  __shared__ __align__(16) ushort_t Bs[2][BM*BK];

  const int t = threadIdx.x, lane = t & 63, w = t >> 6;
  const int wr = w >> 1, wc = w & 1;
  int bid = blockIdx.x;
  int swz = (bid & 7) * (NWG/8) + (bid >> 3);
  int by = swz / GRID_N, bx = swz - by*GRID_N;
  const int brow = by*128, bcol = bx*128;

  f32x4 acc[4][4] = {};
  const int s8 = t & 7, r0 = t >> 3;

  float wsc[4], wof[4];
  #pragma unroll
  for (int i=0;i<4;++i){
    int n = bcol + r0 + 32*i;
    float sc = g_scale[n];
    wsc[i] = sc; wof[i] = -g_zp[n]*sc;
  }
  float4 ax[4][2]; int4 bq[4][2];
  auto loadA = [&](int kt){
    #pragma unroll
    for (int i=0;i<4;++i){
      const float* p = Xf + (size_t)(brow + r0 + 32*i)*K_DIM + kt*BK + s8*8;
      ax[i][0] = *(const float4*)p; ax[i][1] = *(const float4*)(p+4);
    }};
  auto loadB = [&](int kt){
    #pragma unroll
    for (int i=0;i<4;++i){
      const int* p = Wq + (size_t)(bcol + r0 + 32*i)*K_DIM + kt*BK + s8*8;
      bq[i][0] = *(const int4*)p; bq[i][1] = *(const int4*)(p+4);
    }};
  auto stageA = [&](int buf){
    #pragma unroll
    for (int i=0;i<4;++i){
      short8 o;
      o[0]=(short)f2bf(ax[i][0].x); o[1]=(short)f2bf(ax[i][0].y);
      o[2]=(short)f2bf(ax[i][0].z); o[3]=(short)f2bf(ax[i][0].w);
      o[4]=(short)f2bf(ax[i][1].x); o[5]=(short)f2bf(ax[i][1].y);
      o[6]=(short)f2bf(ax[i][1].z); o[7]=(short)f2bf(ax[i][1].w);
      int r = r0 + 32*i; int idx = (r*BK + s8*8) ^ ((r&7)<<3);
      *(short8*)&As[buf][idx] = o; }};
  auto stageB = [&](int buf){
    #pragma unroll
    for (int i=0;i<4;++i){
      short8 o;
      o[0]=(short)f2bf((float)bq[i][0].x*wsc[i]+wof[i]);
      o[1]=(short)f2bf((float)bq[i][0].y*wsc[i]+wof[i]);
      o[2]=(short)f2bf((float)bq[i][0].z*wsc[i]+wof[i]);
      o[3]=(short)f2bf((float)bq[i][0].w*wsc[i]+wof[i]);
      o[4]=(short)f2bf((float)bq[i][1].x*wsc[i]+wof[i]);
      o[5]=(short)f2bf((float)bq[i][1].y*wsc[i]+wof[i]);
      o[6]=(short)f2bf((float)bq[i][1].z*wsc[i]+wof[i]);
      o[7]=(short)f2bf((float)bq[i][1].w*wsc[i]+wof[i]);
      int r = r0 + 32*i; int idx = (r*BK + s8*8) ^ ((r&7)<<3);
      *(short8*)&Bs[buf][idx] = o; }};

  loadA(0); loadB(0);
  stageA(0); stageB(0);
  if (NT > 1){ loadA(1); loadB(1); }

  int cur = 0;
  for (int kt=0; kt<NT; ++kt){
    asm volatile("s_waitcnt vmcnt(0) lgkmcnt(0)" ::: "memory");
    __builtin_amdgcn_sched_barrier(0);
    __syncthreads();
    const int nxt = cur ^ 1;
    if (kt+1 < NT){
      stageA(nxt); stageB(nxt);
      if (kt+2 < NT){ loadA(kt+2); loadB(kt+2); }
    }
    const ushort_t* as = As[cur];
    const ushort_t* bs = Bs[cur];
    #pragma unroll
    for (int kk=0; kk<2; ++kk){
      bf16x8 af[4], bfr[4];
      const int klo = kk*32 + ((lane>>4)<<3);
      #pragma unroll
      for (int mf=0; mf<4; ++mf){
        int r = wr*64 + mf*16 + (lane&15);
        af[mf] = *(const bf16x8*)&as[(r*BK + klo) ^ ((r&7)<<3)];
      }
      #pragma unroll
      for (int nf=0; nf<4; ++nf){
        int r = wc*64 + nf*16 + (lane&15);
        bfr[nf] = *(const bf16x8*)&bs[(r*BK + klo) ^ ((r&7)<<3)];
      }
      #pragma unroll
      for (int mf=0; mf<4; ++mf)
        #pragma unroll
        for (int nf=0; nf<4; ++nf)
          acc[mf][nf] = __builtin_amdgcn_mfma_f32_16x16x32_bf16(af[mf], bfr[nf], acc[mf][nf], 0,0,0);
    }
    cur = nxt;
  }
  const int cl = lane & 15, rq = (lane >> 4) << 2;
  #pragma unroll
  for (int nf=0; nf<4; ++nf){
    int col = bcol + wc*64 + nf*16 + cl;
    float bvs = g_bias[col];
    #pragma unroll
    for (int mf=0; mf<4; ++mf){
      int row = brow + wr*64 + mf*16 + rq;
      f32x4 v = acc[mf][nf];
      #pragma unroll
      for (int i=0;i<4;++i)
        Y[(size_t)(row+i)*N_DIM + col] = v[i] + bvs;
    }
  }
}

// ---------------- launch ----------------
extern "C" void kernel_launch(void* const* d_in, const int* in_sizes, int n_in,
                              void* d_out, int out_size, void* d_ws, size_t ws_size,
                              hipStream_t stream) {
  const float* x     = (const float*)d_in[0];
  const int*   qw    = (const int*)  d_in[1];
  const float* scale = (const float*)d_in[2];
  const float* zp    = (const float*)d_in[3];
  const float* bias  = (const float*)d_in[4];
  float* y = (float*)d_out;

  const size_t XQ = (size_t)M_DIM*K_DIM;        // int8 X
  const size_t WQ = (size_t)N_DIM*K_DIM;        // int8 W
  const size_t SV = (size_t)M_DIM*4;
  const size_t need = XQ + WQ + 2*SV;

  if (ws_size >= need){
    signed char* xq = (signed char*)d_ws;
    signed char* wq = (signed char*)d_ws + XQ;
    float* sxv = (float*)((char*)d_ws + XQ + WQ);
    float* sxs = sxv + M_DIM;
    quant_x<<<dim3(M_DIM), dim3(256), 0, stream>>>(x, xq, sxv, sxs);
    cvt_w8<<<dim3(2048), dim3(256), 0, stream>>>(qw, wq);
    qgemm256_i8<<<dim3((M_DIM/256)*(N_DIM/256)), dim3(512), 0, stream>>>(
        xq, wq, scale, zp, bias, sxv, sxs, y);
  } else {
    qgemm_fb<<<dim3((M_DIM/128)*(N_DIM/128)), dim3(256), 0, stream>>>(
        x, qw, scale, zp, bias, y);
  }
}